// Round 4
// baseline (163.293 us; speedup 1.0000x reference)
//
#include <hip/hip_runtime.h>

#define NPRI 32768
#define NT 64
#define NB 32
#define NCLS 21
#define TBITS 0x3F000000u   // float bits of 0.5

__device__ __forceinline__ float smoothl1(float d){
  float a = fabsf(d);
  return a < 1.0f ? 0.5f*a*a : a - 0.5f;
}

// ---------------------------------------------------------------------------
// K1 (block-specialized fusion):
//  blocks x<32 : match — per-truth argmax over a prior chunk (u64 keys, exact)
//                PLUS per-prior max-over-8-truths packed u32 partials.
//  blocks x>=32: ce — LDS-staged log-sum-exp per prior row (BW-bound).
// Match blocks launch first so VALU-bound match overlaps BW-bound ce.
// ---------------------------------------------------------------------------
__global__ __launch_bounds__(256)
void k_front(const float* __restrict__ conf, const float4* __restrict__ priors,
             const float4* __restrict__ tboxes, float* __restrict__ negconf,
             unsigned* __restrict__ partial, unsigned long long* __restrict__ bpt,
             int* __restrict__ num_pos, float* __restrict__ acc){
  const int b = blockIdx.y, x = blockIdx.x, tid = threadIdx.x;
  __shared__ float xs[256*NCLS];              // ce staging (21504 B)
  if (x >= 32){
    // ---------------- ce ----------------
    const int tile = x - 32;
    const size_t rowbase = (size_t)b*NPRI + (size_t)tile*256;
    float4* s4 = (float4*)xs;
    const float4* g4 = (const float4*)(conf + rowbase*NCLS);  // 16B aligned
    #pragma unroll
    for (int j = 0; j < 5; ++j) s4[tid + j*256] = g4[tid + j*256];
    if (tid < 64) s4[tid + 1280] = g4[tid + 1280];
    __syncthreads();
    const float* row = xs + tid*NCLS;         // stride 21: conflict-free
    float s = 0.f, x0 = row[0];
    #pragma unroll
    for (int j = 0; j < NCLS; ++j) s += __expf(row[j]);
    negconf[rowbase + tid] = __logf(s) - x0;
    return;
  }
  // ---------------- match ----------------
  const int tg = x & 7, chunk = x >> 3;
  if (b == 0 && x == 0){
    if (tid < NB) num_pos[tid] = 0;
    if (tid == NB){ acc[0] = 0.f; acc[1] = 0.f; }
  }
  __shared__ float4 tb[8];
  __shared__ float tarea[8];
  __shared__ unsigned long long redk[4][8];
  if (tid < 8){
    float4 t4 = tboxes[b*NT + tg*8 + tid];
    tb[tid] = t4;
    tarea[tid] = (t4.z - t4.x) * (t4.w - t4.y);
  }
  __syncthreads();
  unsigned long long best[8];
  #pragma unroll
  for (int j = 0; j < 8; ++j) best[j] = 0ull;
  const int pbase = chunk * (NPRI/4);
  for (int it = 0; it < 32; ++it){
    const int p = pbase + it*256 + tid;
    float4 pr = priors[p];
    float hx = pr.z*0.5f, hy = pr.w*0.5f;
    float px1 = pr.x-hx, py1 = pr.y-hy, px2 = pr.x+hx, py2 = pr.y+hy;
    float pa = pr.z*pr.w;
    unsigned invp = ~(unsigned)p;
    unsigned pmax = 0u;
    #pragma unroll
    for (int j = 0; j < 8; ++j){
      float4 t4 = tb[j];
      float w = fminf(t4.z,px2) - fmaxf(t4.x,px1);
      float h = fminf(t4.w,py2) - fmaxf(t4.y,py1);
      w = fmaxf(w,0.f); h = fmaxf(h,0.f);
      float inter = w*h;
      float iou = inter * __builtin_amdgcn_rcpf(tarea[j] + pa - inter);
      unsigned ib = __float_as_uint(iou);
      unsigned long long key = ((unsigned long long)ib << 32) | invp;
      if (key > best[j]) best[j] = key;
      unsigned pk = (ib & 0xFFFFFFC0u) | (unsigned)(63 - (tg*8 + j));
      if (pk > pmax) pmax = pk;
    }
    partial[(size_t)(tg*NB + b)*NPRI + p] = pmax;
  }
  #pragma unroll
  for (int j = 0; j < 8; ++j){
    unsigned long long kk = best[j];
    for (int off = 32; off; off >>= 1){
      unsigned long long o = __shfl_xor(kk, off);
      if (o > kk) kk = o;
    }
    if ((tid & 63) == 0) redk[tid>>6][j] = kk;
  }
  __syncthreads();
  if (tid < 8){
    unsigned long long kk = redk[0][tid];
    #pragma unroll
    for (int w = 1; w < 4; ++w) if (redk[w][tid] > kk) kk = redk[w][tid];
    bpt[((size_t)b*NT + tg*8 + tid)*4 + chunk] = kk;
  }
}

// ---------------------------------------------------------------------------
// K2: per-prior losses. No IoU recompute: best truth comes from 8 packed
// partials; force-match via LDS scatter (atomicMax -> last/largest-t wins,
// matching numpy duplicate-scatter). 512 priors/block, 2048 blocks (100% occ).
// ---------------------------------------------------------------------------
__global__ __launch_bounds__(256)
void k_loss(const float4* __restrict__ priors, const float4* __restrict__ tboxes,
            const int* __restrict__ labels, const float* __restrict__ conf,
            const float4* __restrict__ loc, const unsigned* __restrict__ partial,
            const unsigned long long* __restrict__ bpt, float* __restrict__ negconf,
            int* __restrict__ num_pos, float* __restrict__ acc){
  const int b = blockIdx.y, tid = threadIdx.x;
  const int base = blockIdx.x * 512;
  __shared__ float4 tb[NT];
  __shared__ int slab[NT];
  __shared__ int fm[512];
  fm[tid] = -1; fm[tid + 256] = -1;
  if (tid < NT){
    tb[tid] = tboxes[b*NT + tid];
    slab[tid] = labels[b*NT + tid];
  }
  __syncthreads();
  if (tid < NT){
    const unsigned long long* bk = bpt + ((size_t)b*NT + tid)*4;
    unsigned long long kk = bk[0];
    #pragma unroll
    for (int c = 1; c < 4; ++c) if (bk[c] > kk) kk = bk[c];
    int sp = (int)(~(unsigned)(kk & 0xFFFFFFFFull));   // best prior for truth tid
    unsigned d = (unsigned)(sp - base);
    if (d < 512u) atomicMax(&fm[d], tid);
  }
  __syncthreads();
  float lloc = 0.f, posce = 0.f;
  int cnt = 0;
  #pragma unroll
  for (int k = 0; k < 2; ++k){
    const int sl = tid + 256*k;
    const int p = base + sl;
    unsigned bestp = 0u;
    #pragma unroll
    for (int tg = 0; tg < 8; ++tg){
      unsigned q = partial[(size_t)(tg*NB + b)*NPRI + p];
      if (q > bestp) bestp = q;
    }
    const int f = fm[sl];
    if ((f >= 0) || (bestp >= TBITS)){
      const int t = (f >= 0) ? f : (63 - (int)(bestp & 63u));
      const size_t idx = (size_t)b*NPRI + p;
      float4 pr = priors[p];
      float4 t4 = tb[t];
      float4 lp = loc[idx];
      float gcx = ((t4.x+t4.z)*0.5f - pr.x) / (0.1f*pr.z);
      float gcy = ((t4.y+t4.w)*0.5f - pr.y) / (0.1f*pr.w);
      float gw = __logf((t4.z-t4.x)/pr.z) * 5.f;
      float gh = __logf((t4.w-t4.y)/pr.w) * 5.f;
      lloc += smoothl1(lp.x-gcx)+smoothl1(lp.y-gcy)+smoothl1(lp.z-gw)+smoothl1(lp.w-gh);
      const int cls = slab[t];
      posce += negconf[idx] + conf[idx*NCLS] - conf[idx*NCLS + cls];
      negconf[idx] = 0.f;
      cnt++;
    }
  }
  for (int off = 32; off; off >>= 1){
    lloc  += __shfl_xor(lloc, off);
    posce += __shfl_xor(posce, off);
    cnt   += __shfl_xor(cnt, off);
  }
  __shared__ float r0[4], r1[4];
  __shared__ int r2[4];
  if ((tid & 63) == 0){ int w = tid>>6; r0[w]=lloc; r1[w]=posce; r2[w]=cnt; }
  __syncthreads();
  if (tid == 0){
    float a0=0.f, a1=0.f; int c=0;
    #pragma unroll
    for (int w = 0; w < 4; ++w){ a0+=r0[w]; a1+=r1[w]; c+=r2[w]; }
    atomicAdd(&acc[0], a0);
    atomicAdd(&acc[1], a1);
    atomicAdd(&num_pos[b], c);
  }
}

// ---------------------------------------------------------------------------
// K3: per-batch top-k sum of neg_conf. 31-round binary search on float bits;
// counting via ballot+popcount (scalar pipe), parity LDS buffer -> 1 barrier
// per round. Top-k SUM via threshold is exact under ties.
// ---------------------------------------------------------------------------
__global__ __launch_bounds__(1024)
void k_mine(const float* __restrict__ negconf, const int* __restrict__ num_pos,
            float* __restrict__ acc){
  const int b = blockIdx.x, tid = threadIdx.x;
  const int k = min(3*num_pos[b], NPRI-1);
  if (k <= 0) return;
  const float* nc = negconf + (size_t)b*NPRI;
  unsigned v[32];
  #pragma unroll
  for (int i = 0; i < 32; ++i) v[i] = __float_as_uint(nc[tid + i*1024]);
  __shared__ int scnt[2][16];
  unsigned cur = 0u;
  for (int bit = 30; bit >= 0; --bit){
    const unsigned cand = cur | (1u << bit);
    int c = 0;
    #pragma unroll
    for (int i = 0; i < 32; ++i)
      c += (int)__popcll(__ballot(v[i] >= cand));
    if ((tid & 63) == 0) scnt[bit & 1][tid>>6] = c;
    __syncthreads();
    int tot = 0;
    #pragma unroll
    for (int w = 0; w < 16; ++w) tot += scnt[bit & 1][w];
    if (tot >= k) cur = cand;
  }
  float sgt = 0.f; int cgt = 0;
  #pragma unroll
  for (int i = 0; i < 32; ++i){
    if (v[i] > cur){ sgt += __uint_as_float(v[i]); cgt++; }
  }
  for (int off = 32; off; off >>= 1){
    sgt += __shfl_xor(sgt, off);
    cgt += __shfl_xor(cgt, off);
  }
  __shared__ float ss[16];
  __shared__ int sc[16];
  if ((tid & 63) == 0){ ss[tid>>6] = sgt; sc[tid>>6] = cgt; }
  __syncthreads();
  if (tid == 0){
    float st = 0.f; int ct = 0;
    #pragma unroll
    for (int w = 0; w < 16; ++w){ st += ss[w]; ct += sc[w]; }
    atomicAdd(&acc[1], st + (float)(k - ct) * __uint_as_float(cur));
  }
}

__global__ void k_final(const int* __restrict__ num_pos, const float* __restrict__ acc,
                        float* __restrict__ out){
  if (threadIdx.x == 0){
    int n = 0;
    for (int b = 0; b < NB; ++b) n += num_pos[b];
    float N = (float)n;
    out[0] = acc[0] / N;
    out[1] = acc[1] / N;
  }
}

extern "C" void kernel_launch(void* const* d_in, const int* in_sizes, int n_in,
                              void* d_out, int out_size, void* d_ws, size_t ws_size,
                              hipStream_t stream){
  (void)in_sizes; (void)n_in; (void)out_size; (void)ws_size;
  const float4* loc    = (const float4*)d_in[0];
  const float*  conf   = (const float*) d_in[1];
  const float4* priors = (const float4*)d_in[2];
  const float4* tboxes = (const float4*)d_in[3];
  const int*    labels = (const int*)   d_in[4];
  float* out = (float*)d_out;

  char* ws = (char*)d_ws;
  float* negconf = (float*)ws;                                   // 4 MB
  size_t off = (size_t)NB*NPRI*4;
  unsigned long long* bpt = (unsigned long long*)(ws + off);     // 64 KB
  off += (size_t)NB*NT*4*8;
  unsigned* partial = (unsigned*)(ws + off);                     // 32 MB
  off += (size_t)8*NB*NPRI*4;
  int* num_pos = (int*)(ws + off);
  off += NB*4;
  float* acc = (float*)(ws + off);

  k_front<<<dim3(160, NB), 256, 0, stream>>>(conf, priors, tboxes, negconf,
                                             partial, bpt, num_pos, acc);
  k_loss <<<dim3(NPRI/512, NB), 256, 0, stream>>>(priors, tboxes, labels, conf, loc,
                                                  partial, bpt, negconf, num_pos, acc);
  k_mine <<<NB, 1024, 0, stream>>>(negconf, num_pos, acc);
  k_final<<<1, 64, 0, stream>>>(num_pos, acc, out);
}